// Round 4
// baseline (211.257 us; speedup 1.0000x reference)
//
#include <hip/hip_runtime.h>

typedef unsigned short ushort_t;
typedef __attribute__((ext_vector_type(4))) float f32x4;
typedef __attribute__((ext_vector_type(8))) short short8;
typedef __attribute__((ext_vector_type(4))) unsigned short us4;

#define D_MODEL 1024
#define NHEAD 16
#define DK 64
#define BATCH 2
#define SEQ 2048
#define MTOT 4096
#define EX (MTOT * D_MODEL)      // 4,194,304 elems
#define EW (D_MODEL * D_MODEL)   // 1,048,576 elems

#define MFMA16(a,b,c) __builtin_amdgcn_mfma_f32_16x16x32_bf16((a),(b),(c),0,0,0)

__device__ __forceinline__ ushort_t f2bf(float f){
    union{float f;unsigned u;}c; c.f=f;
    unsigned u=c.u, r=u+0x7FFFu+((u>>16)&1u);   // RNE
    return (ushort_t)(r>>16);
}
__device__ __forceinline__ void gload16(const ushort_t* g, ushort_t* l){
    __builtin_amdgcn_global_load_lds((const __attribute__((address_space(1))) unsigned*)g,
                                     (__attribute__((address_space(3))) unsigned*)l, 16, 0, 0);
}
// bijective XCD swizzle (nwg % 8 == 0)
__device__ __forceinline__ int xcd_swz(int nwg){
    int s = blockIdx.x;
    return (s & 7) * (nwg >> 3) + (s >> 3);
}

// ---------------------------------------------------------------- casts
__global__ void cast1(const float* __restrict__ x, ushort_t* __restrict__ y, int n4){
    int i = blockIdx.x*blockDim.x + threadIdx.x, st = gridDim.x*blockDim.x;
    for(; i < n4; i += st){
        f32x4 v = ((const f32x4*)x)[i];
        us4 o; o[0]=f2bf(v[0]); o[1]=f2bf(v[1]); o[2]=f2bf(v[2]); o[3]=f2bf(v[3]);
        ((us4*)y)[i] = o;
    }
}
__global__ void cast3(const float* __restrict__ a, const float* __restrict__ b,
                      const float* __restrict__ c, ushort_t* __restrict__ dst, int n4){
    const float* s = blockIdx.y==0 ? a : (blockIdx.y==1 ? b : c);
    us4* d = (us4*)(dst + (size_t)blockIdx.y * n4 * 4);
    const f32x4* sv = (const f32x4*)s;
    int i = blockIdx.x*blockDim.x + threadIdx.x, st = gridDim.x*blockDim.x;
    for(; i < n4; i += st){
        f32x4 v = sv[i];
        us4 o; o[0]=f2bf(v[0]); o[1]=f2bf(v[1]); o[2]=f2bf(v[2]); o[3]=f2bf(v[3]);
        d[i] = o;
    }
}

// ---------------------------------------------------------------- GEMM body
// C[m,n] = (sum_k A[m,k]*B[n,k] + bias[n]) * scale ; M=4096, N=K=1024 fixed.
// 128x128 tile, BK=32, 4 waves, 2-phase double-buffered LDS pipeline.
// mode 0: bf16 [M][N] ; mode 1: bf16 V-transposed [b][h][d][s] ; mode 2: fp32 [M][N]
__device__ __forceinline__ void gemm_body(
    const ushort_t* __restrict__ A, const ushort_t* __restrict__ Bm,
    const float* __restrict__ bias, float scale, int bm, int bn, int mode,
    void* __restrict__ out,
    ushort_t* As0, ushort_t* As1, ushort_t* Bs0, ushort_t* Bs1)
{
    const int tid = threadIdx.x, lane = tid & 63, wid = tid >> 6;
    const int row0 = bm << 7, col0 = bn << 7;
    const int wrow = (wid >> 1) << 6, wcol = (wid & 1) << 6;
    const int l4 = lane >> 2, lc = (lane & 3) << 3, lr = lane & 15, ko = (lane >> 4) << 3;
    const f32x4 Z4 = {0.f,0.f,0.f,0.f};

    f32x4 acc[4][4];
#pragma unroll
    for(int i=0;i<4;i++)
#pragma unroll
        for(int j=0;j<4;j++) acc[i][j] = Z4;

#define GSTAGE(AS,BS,k0) do{ \
    gload16(A +(size_t)(row0+32*wid   +l4)*D_MODEL+(k0)+lc, (AS)+(2*wid  )*512); \
    gload16(A +(size_t)(row0+32*wid+16+l4)*D_MODEL+(k0)+lc, (AS)+(2*wid+1)*512); \
    gload16(Bm+(size_t)(col0+32*wid   +l4)*D_MODEL+(k0)+lc, (BS)+(2*wid  )*512); \
    gload16(Bm+(size_t)(col0+32*wid+16+l4)*D_MODEL+(k0)+lc, (BS)+(2*wid+1)*512); \
}while(0)
#define GCOMP(AS,BS) do{ \
    short8 af[4], bf[4]; \
    _Pragma("unroll") for(int i=0;i<4;i++) af[i]=*(const short8*)((AS)+(wrow+i*16+lr)*32+ko); \
    _Pragma("unroll") for(int j=0;j<4;j++) bf[j]=*(const short8*)((BS)+(wcol+j*16+lr)*32+ko); \
    __builtin_amdgcn_s_setprio(1); \
    _Pragma("unroll") for(int i=0;i<4;i++) \
    _Pragma("unroll") for(int j=0;j<4;j++) acc[i][j]=MFMA16(af[i],bf[j],acc[i][j]); \
    __builtin_amdgcn_s_setprio(0); \
}while(0)

    GSTAGE(As0,Bs0,0);
    __syncthreads();                       // barrier drains vmcnt: tile0 ready
#pragma unroll 1
    for(int t=0; t<32; t+=2){
        if(t+1<32) GSTAGE(As1,Bs1,(t+1)*32);   // issue next while computing current
        GCOMP(As0,Bs0);
        __syncthreads();                       // drain: As1 staged, As0 free
        if(t+2<32) GSTAGE(As0,Bs0,(t+2)*32);
        GCOMP(As1,Bs1);
        __syncthreads();
    }
#undef GSTAGE
#undef GCOMP

    const int rr4 = (lane >> 4) << 2;
#pragma unroll
    for(int i=0;i<4;i++){
#pragma unroll
        for(int j=0;j<4;j++){
            const int m0 = row0 + wrow + i*16 + rr4;
            const int n  = col0 + wcol + j*16 + lr;
            const float bs = bias[n];
            if(mode == 2){
                float* O = (float*)out;
#pragma unroll
                for(int r=0;r<4;r++) O[(size_t)(m0+r)*D_MODEL+n] = (acc[i][j][r]+bs)*scale;
            } else if(mode == 0){
                ushort_t* O = (ushort_t*)out;
#pragma unroll
                for(int r=0;r<4;r++) O[(size_t)(m0+r)*D_MODEL+n] = f2bf((acc[i][j][r]+bs)*scale);
            } else {
                // V transposed: Vt[b][h][d][s], s = m&2047 consecutive over r -> one 8B store
                ushort_t* O = (ushort_t*)out;
                const int bb = m0 >> 11, s = m0 & 2047, h = n >> 6, d = n & 63;
                us4 p;
#pragma unroll
                for(int r=0;r<4;r++) p[r] = f2bf((acc[i][j][r]+bs)*scale);
                *(us4*)(O + ((size_t)(bb*NHEAD + h)*DK + d)*SEQ + s) = p;
            }
        }
    }
}

// Q scale: (1/sqrt(dk)) * log2(e) so attention can use native exp2  (softmax is
// exact under the log2-domain shift: 2^(s-m)/sum = softmax(s*ln2))
#define QSCALE (0.125f * 1.44269504088896f)

__global__ __launch_bounds__(256,2)
void qkv_fused(const ushort_t* __restrict__ Xq, const ushort_t* __restrict__ Xk,
               const ushort_t* __restrict__ Xv,
               const ushort_t* __restrict__ Wq, const ushort_t* __restrict__ Wk,
               const ushort_t* __restrict__ Wv,
               const float* __restrict__ bq, const float* __restrict__ bk,
               const float* __restrict__ bv,
               ushort_t* Qp, ushort_t* Kp, ushort_t* VtG)
{
    __shared__ ushort_t As0[4096], As1[4096], Bs0[4096], Bs1[4096];
    const int wk = xcd_swz(768);
    const int which = wk >> 8, t = wk & 255;
    const ushort_t *A, *Bm; const float* bias; float scale; int mode; void* out;
    if(which == 0){ A=Xq; Bm=Wq; bias=bq; scale=QSCALE; mode=0; out=Qp; }
    else if(which == 1){ A=Xk; Bm=Wk; bias=bk; scale=1.f; mode=0; out=Kp; }
    else { A=Xv; Bm=Wv; bias=bv; scale=1.f; mode=1; out=VtG; }
    gemm_body(A,Bm,bias,scale, t>>3, t&7, mode, out, As0,As1,Bs0,Bs1);
}

__global__ __launch_bounds__(256,2)
void gemm_one(const ushort_t* __restrict__ A, const ushort_t* __restrict__ Bm,
              const float* __restrict__ bias, float scale, int mode, void* out)
{
    __shared__ ushort_t As0[4096], As1[4096], Bs0[4096], Bs1[4096];
    const int wk = xcd_swz(256);
    gemm_body(A,Bm,bias,scale, wk>>3, wk&7, mode, out, As0,As1,Bs0,Bs1);
}

// ---------------------------------------------------------------- flash attention
// grid 1024 (32 bh * 32 q-tiles). Block 256 = 4 waves, wave = 16 q-rows.
// Double-buffered K/V staging (T3-minimal): issue tile t+1's global_load_lds before
// computing tile t; ONE barrier per tile both drains the prefetch and fences readers.
// K staged [64][64] XOR-swizzled via pre-swizzled global source; V pre-transposed global.
__global__ __launch_bounds__(256,3)
void attn_fwd(const ushort_t* __restrict__ Qp, const ushort_t* __restrict__ Kp,
              const ushort_t* __restrict__ VtG, ushort_t* __restrict__ ctx)
{
    __shared__ ushort_t Ks[2][64*64];
    __shared__ ushort_t Vs[2][64*64];
    __shared__ ushort_t Ps[64*72];

    const int wk = xcd_swz(1024);
    const int bh = wk >> 5, qt = wk & 31;
    const int b = bh >> 4, h = bh & 15;
    const int tid = threadIdx.x, lane = tid & 63, wid = tid >> 6;
    const int lq = lane & 15, hi = lane >> 4;
    const size_t qkbase = (size_t)b*SEQ*D_MODEL + h*DK;
    const size_t vbase  = (size_t)bh * DK * SEQ;
    const int q0 = qt*64 + wid*16;
    const f32x4 Z4 = {0.f,0.f,0.f,0.f};

    // Q fragments (A-operand): lane row = lq, d-elems hi*8 within each 32-slice
    short8 qa[2];
#pragma unroll
    for(int ks=0;ks<2;ks++)
        qa[ks] = *(const short8*)(Qp + qkbase + (size_t)(q0+lq)*D_MODEL + ks*32 + hi*8);

    f32x4 o[4];
    float run_m[4], run_l[4];
#pragma unroll
    for(int r=0;r<4;r++){ o[r]=Z4; run_m[r]=-1e30f; run_l[r]=0.f; }

    const int rsub = lane >> 3;            // 0..7
    const int jsw  = (lane & 7) ^ rsub;    // inverse-swizzled source chunk

#define ASTAGE(buf, kv) do{ \
    _Pragma("unroll") for(int c=0;c<2;c++){ \
        const int r_ = wid*16 + c*8 + rsub; \
        gload16(Kp  + qkbase + (size_t)((kv)+r_)*D_MODEL + jsw*8, Ks[buf] + (wid*16+c*8)*64); \
        gload16(VtG + vbase  + (size_t)r_*SEQ + (kv) + jsw*8,     Vs[buf] + (wid*16+c*8)*64); \
    } \
}while(0)

    ASTAGE(0, 0);
    __syncthreads();                       // tile 0 staged

#pragma unroll 1
    for(int kv0=0; kv0<SEQ; kv0+=64){
        const int cur = (kv0 >> 6) & 1;
        if(kv0 + 64 < SEQ) ASTAGE(cur^1, kv0+64);   // prefetch flies under softmax+PV

        // ---- S = Q K^T
        f32x4 st[4];
        __builtin_amdgcn_s_setprio(1);
#pragma unroll
        for(int ct=0;ct<4;ct++){
            short8 k0 = *(const short8*)(Ks[cur] + (ct*16+lq)*64 + (((0+hi)^(lq&7))<<3));
            short8 k1 = *(const short8*)(Ks[cur] + (ct*16+lq)*64 + (((4+hi)^(lq&7))<<3));
            f32x4 s = MFMA16(qa[0], k0, Z4);
            st[ct]  = MFMA16(qa[1], k1, s);
        }
        __builtin_amdgcn_s_setprio(0);

        // ---- online softmax (log2 domain); lane holds S[q=hi*4+r][k=ct*16+lq]
#pragma unroll
        for(int r=0;r<4;r++){
            float mx = fmaxf(fmaxf(st[0][r],st[1][r]), fmaxf(st[2][r],st[3][r]));
#pragma unroll
            for(int off=8;off>=1;off>>=1) mx = fmaxf(mx, __shfl_xor(mx,off));
            const float nm = fmaxf(run_m[r], mx);
            const float corr = exp2f(run_m[r] - nm);
            run_m[r] = nm;
            float rs = 0.f;
#pragma unroll
            for(int ct=0;ct<4;ct++){
                float p = exp2f(st[ct][r] - nm);
                st[ct][r] = p; rs += p;
            }
#pragma unroll
            for(int off=8;off>=1;off>>=1) rs += __shfl_xor(rs,off);
            run_l[r] = run_l[r]*corr + rs;
#pragma unroll
            for(int dt=0;dt<4;dt++) o[dt][r] *= corr;
        }

        // ---- P -> LDS (wave-private rows; same-wave RAW ordered by lgkmcnt)
#pragma unroll
        for(int ct=0;ct<4;ct++)
#pragma unroll
            for(int r=0;r<4;r++)
                Ps[(wid*16 + hi*4 + r)*72 + ct*16 + lq] = f2bf(st[ct][r]);

        // ---- O += P V
        short8 pa0 = *(const short8*)(Ps + (wid*16+lq)*72 + hi*8);
        short8 pa1 = *(const short8*)(Ps + (wid*16+lq)*72 + 32 + hi*8);
        __builtin_amdgcn_s_setprio(1);
#pragma unroll
        for(int dt=0;dt<4;dt++){
            short8 v0 = *(const short8*)(Vs[cur] + (dt*16+lq)*64 + (((0+hi)^(lq&7))<<3));
            short8 v1 = *(const short8*)(Vs[cur] + (dt*16+lq)*64 + (((4+hi)^(lq&7))<<3));
            o[dt] = MFMA16(pa0, v0, o[dt]);
            o[dt] = MFMA16(pa1, v1, o[dt]);
        }
        __builtin_amdgcn_s_setprio(0);
        __syncthreads();    // drains prefetch (next buf ready) + readers done with cur buf
    }
#undef ASTAGE

    // ---- epilogue: ctx[b][s][h*64+d] bf16
    float inv[4];
#pragma unroll
    for(int r=0;r<4;r++) inv[r] = 1.f/run_l[r];
#pragma unroll
    for(int dt=0;dt<4;dt++)
#pragma unroll
        for(int r=0;r<4;r++)
            ctx[qkbase + (size_t)(q0 + hi*4 + r)*D_MODEL + dt*16 + lq] = f2bf(o[dt][r]*inv[r]);
}

// ----------------------------------------------------------------
extern "C" void kernel_launch(void* const* d_in, const int* in_sizes, int n_in,
                              void* d_out, int out_size, void* d_ws, size_t ws_size,
                              hipStream_t stream) {
    (void)in_sizes; (void)n_in; (void)out_size;
    const float* q  = (const float*)d_in[0];
    const float* k  = (const float*)d_in[1];
    const float* v  = (const float*)d_in[2];
    const float* Wq = (const float*)d_in[3];
    const float* bq = (const float*)d_in[4];
    const float* Wk = (const float*)d_in[5];
    const float* bk = (const float*)d_in[6];
    const float* Wv = (const float*)d_in[7];
    const float* bv = (const float*)d_in[8];
    const float* Wo = (const float*)d_in[9];
    const float* bo = (const float*)d_in[10];
    float* out = (float*)d_out;

    ushort_t* WS = (ushort_t*)d_ws;
    const dim3 blk(256);
    const int n4x = EX/4, n4w = EW/4;

    if(ws_size >= (size_t)(6*(size_t)EX + 3*(size_t)EW) * 2){
        // tier A: fused QKV (3 blocks/CU)
        ushort_t* Xq  = WS;
        ushort_t* Xk  = Xq + EX;
        ushort_t* Xv  = Xk + EX;
        ushort_t* Wqb = Xv + EX;
        ushort_t* Wkb = Wqb + EW;
        ushort_t* Wvb = Wkb + EW;
        ushort_t* Qp  = Wvb + EW;
        ushort_t* Kp  = Qp + EX;
        ushort_t* VtG = Kp + EX;
        ushort_t* ctx = Xq;     // free after qkv_fused
        ushort_t* Wob = Wqb;    // free after qkv_fused

        cast3<<<dim3(1024,3), blk, 0, stream>>>(q, k, v, Xq, n4x);
        cast3<<<dim3(256,3),  blk, 0, stream>>>(Wq, Wk, Wv, Wqb, n4w);
        qkv_fused<<<768, blk, 0, stream>>>(Xq,Xk,Xv, Wqb,Wkb,Wvb, bq,bk,bv, Qp,Kp,VtG);
        cast1<<<512, blk, 0, stream>>>(Wo, Wob, n4w);
        attn_fwd<<<1024, blk, 0, stream>>>(Qp, Kp, VtG, ctx);
        gemm_one<<<256, blk, 0, stream>>>(ctx, Wob, bo, 1.f, 2, out);
    } else {
        // tier C: sequential, 35.6 MB (proven size)
        ushort_t* Xb  = WS;
        ushort_t* Wb  = Xb + EX;
        ushort_t* Qp  = Wb + EW;
        ushort_t* Kp  = Qp + EX;
        ushort_t* VtG = Kp + EX;
        ushort_t* ctx = Xb;

        cast1<<<1024, blk, 0, stream>>>(q, Xb, n4x);
        cast1<<<512,  blk, 0, stream>>>(Wq, Wb, n4w);
        gemm_one<<<256, blk, 0, stream>>>(Xb, Wb, bq, QSCALE, 0, Qp);
        cast1<<<1024, blk, 0, stream>>>(k, Xb, n4x);
        cast1<<<512,  blk, 0, stream>>>(Wk, Wb, n4w);
        gemm_one<<<256, blk, 0, stream>>>(Xb, Wb, bk, 1.f, 0, Kp);
        cast1<<<1024, blk, 0, stream>>>(v, Xb, n4x);
        cast1<<<512,  blk, 0, stream>>>(Wv, Wb, n4w);
        gemm_one<<<256, blk, 0, stream>>>(Xb, Wb, bv, 1.f, 1, VtG);
        attn_fwd<<<1024, blk, 0, stream>>>(Qp, Kp, VtG, ctx);
        cast1<<<512, blk, 0, stream>>>(Wo, Wb, n4w);
        gemm_one<<<256, blk, 0, stream>>>(ctx, Wb, bo, 1.f, 2, out);
    }
}

// Round 5
// 167.700 us; speedup vs baseline: 1.2597x; 1.2597x over previous
//
#include <hip/hip_runtime.h>
#include <hip/hip_bf16.h>

typedef unsigned short ushort_t;
typedef __attribute__((ext_vector_type(4))) float f32x4;
typedef __attribute__((ext_vector_type(8))) short short8;
typedef __attribute__((ext_vector_type(4))) unsigned short us4;

#define D_MODEL 1024
#define NHEAD 16
#define DK 64
#define BATCH 2
#define SEQ 2048
#define MTOT 4096
#define EX (MTOT * D_MODEL)      // 4,194,304 elems
#define EW (D_MODEL * D_MODEL)   // 1,048,576 elems

#define MFMA16(a,b,c) __builtin_amdgcn_mfma_f32_16x16x32_bf16((a),(b),(c),0,0,0)

__device__ __forceinline__ ushort_t f2bf(float f){
    union{float f;unsigned u;}c; c.f=f;
    unsigned u=c.u, r=u+0x7FFFu+((u>>16)&1u);   // RNE
    return (ushort_t)(r>>16);
}
// packed f32 pair -> bf16x2 in u32 (low = a). Compiler emits v_cvt_pk_bf16_f32.
__device__ __forceinline__ unsigned cvtpk_bf(float a, float b){
    float2 t; t.x = a; t.y = b;
    union{ __hip_bfloat162 h; unsigned u; } c;
    c.h = __float22bfloat162_rn(t);
    return c.u;
}
__device__ __forceinline__ void gload16(const ushort_t* g, ushort_t* l){
    __builtin_amdgcn_global_load_lds((const __attribute__((address_space(1))) unsigned*)g,
                                     (__attribute__((address_space(3))) unsigned*)l, 16, 0, 0);
}
// bijective XCD swizzle (nwg % 8 == 0)
__device__ __forceinline__ int xcd_swz(int nwg){
    int s = blockIdx.x;
    return (s & 7) * (nwg >> 3) + (s >> 3);
}

// ---------------------------------------------------------------- casts
__global__ void cast1(const float* __restrict__ x, ushort_t* __restrict__ y, int n4){
    int i = blockIdx.x*blockDim.x + threadIdx.x, st = gridDim.x*blockDim.x;
    for(; i < n4; i += st){
        f32x4 v = ((const f32x4*)x)[i];
        us4 o; o[0]=f2bf(v[0]); o[1]=f2bf(v[1]); o[2]=f2bf(v[2]); o[3]=f2bf(v[3]);
        ((us4*)y)[i] = o;
    }
}
__global__ void cast3(const float* __restrict__ a, const float* __restrict__ b,
                      const float* __restrict__ c, ushort_t* __restrict__ dst, int n4){
    const float* s = blockIdx.y==0 ? a : (blockIdx.y==1 ? b : c);
    us4* d = (us4*)(dst + (size_t)blockIdx.y * n4 * 4);
    const f32x4* sv = (const f32x4*)s;
    int i = blockIdx.x*blockDim.x + threadIdx.x, st = gridDim.x*blockDim.x;
    for(; i < n4; i += st){
        f32x4 v = sv[i];
        us4 o; o[0]=f2bf(v[0]); o[1]=f2bf(v[1]); o[2]=f2bf(v[2]); o[3]=f2bf(v[3]);
        d[i] = o;
    }
}

// ---------------------------------------------------------------- GEMM body
// C[m,n] = (sum_k A[m,k]*B[n,k] + bias[n]) * scale ; M=4096, N=K=1024 fixed.
// 128x128 tile, BK=32, 4 waves, 2-phase double-buffered LDS pipeline.
// mode 0: bf16 [M][N] ; mode 1: bf16 V-transposed [b][h][d][s] ; mode 2: fp32 [M][N]
__device__ __forceinline__ void gemm_body(
    const ushort_t* __restrict__ A, const ushort_t* __restrict__ Bm,
    const float* __restrict__ bias, float scale, int bm, int bn, int mode,
    void* __restrict__ out,
    ushort_t* As0, ushort_t* As1, ushort_t* Bs0, ushort_t* Bs1)
{
    const int tid = threadIdx.x, lane = tid & 63, wid = tid >> 6;
    const int row0 = bm << 7, col0 = bn << 7;
    const int wrow = (wid >> 1) << 6, wcol = (wid & 1) << 6;
    const int l4 = lane >> 2, lc = (lane & 3) << 3, lr = lane & 15, ko = (lane >> 4) << 3;
    const f32x4 Z4 = {0.f,0.f,0.f,0.f};

    f32x4 acc[4][4];
#pragma unroll
    for(int i=0;i<4;i++)
#pragma unroll
        for(int j=0;j<4;j++) acc[i][j] = Z4;

#define GSTAGE(AS,BS,k0) do{ \
    gload16(A +(size_t)(row0+32*wid   +l4)*D_MODEL+(k0)+lc, (AS)+(2*wid  )*512); \
    gload16(A +(size_t)(row0+32*wid+16+l4)*D_MODEL+(k0)+lc, (AS)+(2*wid+1)*512); \
    gload16(Bm+(size_t)(col0+32*wid   +l4)*D_MODEL+(k0)+lc, (BS)+(2*wid  )*512); \
    gload16(Bm+(size_t)(col0+32*wid+16+l4)*D_MODEL+(k0)+lc, (BS)+(2*wid+1)*512); \
}while(0)
#define GCOMP(AS,BS) do{ \
    short8 af[4], bf[4]; \
    _Pragma("unroll") for(int i=0;i<4;i++) af[i]=*(const short8*)((AS)+(wrow+i*16+lr)*32+ko); \
    _Pragma("unroll") for(int j=0;j<4;j++) bf[j]=*(const short8*)((BS)+(wcol+j*16+lr)*32+ko); \
    __builtin_amdgcn_s_setprio(1); \
    _Pragma("unroll") for(int i=0;i<4;i++) \
    _Pragma("unroll") for(int j=0;j<4;j++) acc[i][j]=MFMA16(af[i],bf[j],acc[i][j]); \
    __builtin_amdgcn_s_setprio(0); \
}while(0)

    GSTAGE(As0,Bs0,0);
    __syncthreads();                       // barrier drains vmcnt: tile0 ready
#pragma unroll 1
    for(int t=0; t<32; t+=2){
        if(t+1<32) GSTAGE(As1,Bs1,(t+1)*32);   // issue next while computing current
        GCOMP(As0,Bs0);
        __syncthreads();                       // drain: As1 staged, As0 free
        if(t+2<32) GSTAGE(As0,Bs0,(t+2)*32);
        GCOMP(As1,Bs1);
        __syncthreads();
    }
#undef GSTAGE
#undef GCOMP

    const int rr4 = (lane >> 4) << 2;
#pragma unroll
    for(int i=0;i<4;i++){
#pragma unroll
        for(int j=0;j<4;j++){
            const int m0 = row0 + wrow + i*16 + rr4;
            const int n  = col0 + wcol + j*16 + lr;
            const float bs = bias[n];
            if(mode == 2){
                float* O = (float*)out;
#pragma unroll
                for(int r=0;r<4;r++) O[(size_t)(m0+r)*D_MODEL+n] = (acc[i][j][r]+bs)*scale;
            } else if(mode == 0){
                ushort_t* O = (ushort_t*)out;
#pragma unroll
                for(int r=0;r<4;r++) O[(size_t)(m0+r)*D_MODEL+n] = f2bf((acc[i][j][r]+bs)*scale);
            } else {
                // V transposed: Vt[b][h][d][s], s = m&2047 consecutive over r -> one 8B store
                ushort_t* O = (ushort_t*)out;
                const int bb = m0 >> 11, s = m0 & 2047, h = n >> 6, d = n & 63;
                us4 p;
#pragma unroll
                for(int r=0;r<4;r++) p[r] = f2bf((acc[i][j][r]+bs)*scale);
                *(us4*)(O + ((size_t)(bb*NHEAD + h)*DK + d)*SEQ + s) = p;
            }
        }
    }
}

// Q scale: (1/sqrt(dk)) * log2(e) so attention can use native exp2
#define QSCALE (0.125f * 1.44269504088896f)

__global__ __launch_bounds__(256,2)
void qkv_fused(const ushort_t* __restrict__ Xq, const ushort_t* __restrict__ Xk,
               const ushort_t* __restrict__ Xv,
               const ushort_t* __restrict__ Wq, const ushort_t* __restrict__ Wk,
               const ushort_t* __restrict__ Wv,
               const float* __restrict__ bq, const float* __restrict__ bk,
               const float* __restrict__ bv,
               ushort_t* Qp, ushort_t* Kp, ushort_t* VtG)
{
    __shared__ ushort_t As0[4096], As1[4096], Bs0[4096], Bs1[4096];
    const int wk = xcd_swz(768);
    const int which = wk >> 8, t = wk & 255;
    const ushort_t *A, *Bm; const float* bias; float scale; int mode; void* out;
    if(which == 0){ A=Xq; Bm=Wq; bias=bq; scale=QSCALE; mode=0; out=Qp; }
    else if(which == 1){ A=Xk; Bm=Wk; bias=bk; scale=1.f; mode=0; out=Kp; }
    else { A=Xv; Bm=Wv; bias=bv; scale=1.f; mode=1; out=VtG; }
    gemm_body(A,Bm,bias,scale, t>>3, t&7, mode, out, As0,As1,Bs0,Bs1);
}

__global__ __launch_bounds__(256,2)
void gemm_one(const ushort_t* __restrict__ A, const ushort_t* __restrict__ Bm,
              const float* __restrict__ bias, float scale, int mode, void* out)
{
    __shared__ ushort_t As0[4096], As1[4096], Bs0[4096], Bs1[4096];
    const int wk = xcd_swz(256);
    gemm_body(A,Bm,bias,scale, wk>>3, wk&7, mode, out, As0,As1,Bs0,Bs1);
}

// ---------------------------------------------------------------- flash attention
// grid 1024 = 32 bh * 32 q-tiles; block 256 = 4 waves * 16 q-rows; KVBLK=64.
// Swapped QK^T: st = mfma(K,Q) = S^T -> each lane owns one q-row's 16 scores in
// registers; softmax is in-lane tree + 2 shfl_xor. P never touches LDS: packed
// with v_cvt_pk and redistributed to the PV A-fragment via 16 shfl + 8 selects.
// K/V double-buffered (32 KB LDS -> 4 blocks/CU, clean grid tail), 1 barrier/tile.
__global__ __launch_bounds__(256,4)
void attn_fwd(const ushort_t* __restrict__ Qp, const ushort_t* __restrict__ Kp,
              const ushort_t* __restrict__ VtG, ushort_t* __restrict__ ctx)
{
    __shared__ ushort_t Ks[2][64*64];
    __shared__ ushort_t Vs[2][64*64];

    const int wk = xcd_swz(1024);
    const int bh = wk >> 5, qt = wk & 31;
    const int b = bh >> 4, h = bh & 15;
    const int tid = threadIdx.x, lane = tid & 63, wid = tid >> 6;
    const int lq = lane & 15, hi = lane >> 4;
    const size_t qkbase = (size_t)b*SEQ*D_MODEL + h*DK;
    const size_t vbase  = (size_t)bh * DK * SEQ;
    const int q0 = qt*64 + wid*16;
    const f32x4 Z4 = {0.f,0.f,0.f,0.f};

    // Q fragments (now the B operand): lane row = lq, d-slice hi*8
    short8 qa[2];
#pragma unroll
    for(int ks=0;ks<2;ks++)
        qa[ks] = *(const short8*)(Qp + qkbase + (size_t)(q0+lq)*D_MODEL + ks*32 + hi*8);

    f32x4 o[4];
    float run_m = -1e30f, run_l = 0.f;
#pragma unroll
    for(int dt=0;dt<4;dt++) o[dt] = Z4;

    const int rsub = lane >> 3;            // 0..7
    const int jsw  = (lane & 7) ^ rsub;    // inverse-swizzled source chunk

#define ASTAGE(buf, kv) do{ \
    _Pragma("unroll") for(int c=0;c<2;c++){ \
        const int r_ = wid*16 + c*8 + rsub; \
        gload16(Kp  + qkbase + (size_t)((kv)+r_)*D_MODEL + jsw*8, Ks[buf] + (wid*16+c*8)*64); \
        gload16(VtG + vbase  + (size_t)r_*SEQ + (kv) + jsw*8,     Vs[buf] + (wid*16+c*8)*64); \
    } \
}while(0)

    ASTAGE(0, 0);
    __syncthreads();

#pragma unroll 1
    for(int kv0=0; kv0<SEQ; kv0+=64){
        const int cur = (kv0 >> 6) & 1;
        if(kv0 + 64 < SEQ) ASTAGE(cur^1, kv0+64);   // prefetch flies under compute

        // ---- S^T = K Q^T : lane (lq,hi) gets S[q=q0+lq][k=16ct+4hi+r]
        f32x4 st[4];
        __builtin_amdgcn_s_setprio(1);
#pragma unroll
        for(int ct=0;ct<4;ct++){
            short8 k0 = *(const short8*)(Ks[cur] + (ct*16+lq)*64 + (((0+hi)^(lq&7))<<3));
            short8 k1 = *(const short8*)(Ks[cur] + (ct*16+lq)*64 + (((4+hi)^(lq&7))<<3));
            f32x4 s = MFMA16(k0, qa[0], Z4);
            st[ct]  = MFMA16(k1, qa[1], s);
        }
        __builtin_amdgcn_s_setprio(0);

        // ---- per-lane online softmax (log2 domain), q = q0+lq
        float mx = fmaxf(fmaxf(fmaxf(st[0][0],st[0][1]),fmaxf(st[0][2],st[0][3])),
                   fmaxf(fmaxf(fmaxf(st[1][0],st[1][1]),fmaxf(st[1][2],st[1][3])),
                   fmaxf(fmaxf(fmaxf(st[2][0],st[2][1]),fmaxf(st[2][2],st[2][3])),
                         fmaxf(fmaxf(st[3][0],st[3][1]),fmaxf(st[3][2],st[3][3])))));
        mx = fmaxf(mx, __shfl_xor(mx, 16));
        mx = fmaxf(mx, __shfl_xor(mx, 32));
        const float nm = fmaxf(run_m, mx);
        const float corr = exp2f(run_m - nm);
        run_m = nm;
        float rs = 0.f;
#pragma unroll
        for(int ct=0;ct<4;ct++)
#pragma unroll
            for(int r=0;r<4;r++){
                float p = exp2f(st[ct][r] - nm);
                st[ct][r] = p; rs += p;
            }
        rs += __shfl_xor(rs, 16);
        rs += __shfl_xor(rs, 32);
        run_l = run_l*corr + rs;

        // ---- rescale o: o-row q = 4hi+r needs corr from lane (4hi+r)
        float cr[4];
#pragma unroll
        for(int r=0;r<4;r++) cr[r] = __shfl(corr, 4*hi + r);
#pragma unroll
        for(int dt=0;dt<4;dt++)
#pragma unroll
            for(int r=0;r<4;r++) o[dt][r] *= cr[r];

        // ---- pack P to bf16 pairs: pk[ct][w] holds k = 16ct+4hi+{2w,2w+1}
        unsigned pk[4][2];
#pragma unroll
        for(int ct=0;ct<4;ct++){
            pk[ct][0] = cvtpk_bf(st[ct][0], st[ct][1]);
            pk[ct][1] = cvtpk_bf(st[ct][2], st[ct][3]);
        }

        // ---- redistribute to PV A-frags: lane (lq,hi) needs P[q=lq][k=8hi+j] (+32)
        // word w' from lane lq+32*(hi&1)+16*(w'>>1), pack[hi>>1 (+2)][w'&1]
        const int srcA = lq + ((hi & 1) << 5);
        const int srcB = srcA + 16;
        const bool csel = (hi & 2) != 0;
        union { unsigned u[4]; short8 s; } P0, P1;
        {
            unsigned a0 = __shfl((int)pk[0][0], srcA), b0 = __shfl((int)pk[1][0], srcA);
            unsigned a1 = __shfl((int)pk[0][1], srcA), b1 = __shfl((int)pk[1][1], srcA);
            unsigned a2 = __shfl((int)pk[0][0], srcB), b2 = __shfl((int)pk[1][0], srcB);
            unsigned a3 = __shfl((int)pk[0][1], srcB), b3 = __shfl((int)pk[1][1], srcB);
            P0.u[0] = csel ? b0 : a0;  P0.u[1] = csel ? b1 : a1;
            P0.u[2] = csel ? b2 : a2;  P0.u[3] = csel ? b3 : a3;
            unsigned c0 = __shfl((int)pk[2][0], srcA), d0 = __shfl((int)pk[3][0], srcA);
            unsigned c1 = __shfl((int)pk[2][1], srcA), d1 = __shfl((int)pk[3][1], srcA);
            unsigned c2 = __shfl((int)pk[2][0], srcB), d2 = __shfl((int)pk[3][0], srcB);
            unsigned c3 = __shfl((int)pk[2][1], srcB), d3 = __shfl((int)pk[3][1], srcB);
            P1.u[0] = csel ? d0 : c0;  P1.u[1] = csel ? d1 : c1;
            P1.u[2] = csel ? d2 : c2;  P1.u[3] = csel ? d3 : c3;
        }

        // ---- O += P V
        __builtin_amdgcn_s_setprio(1);
#pragma unroll
        for(int dt=0;dt<4;dt++){
            short8 v0 = *(const short8*)(Vs[cur] + (dt*16+lq)*64 + (((0+hi)^(lq&7))<<3));
            short8 v1 = *(const short8*)(Vs[cur] + (dt*16+lq)*64 + (((4+hi)^(lq&7))<<3));
            o[dt] = MFMA16(P0.s, v0, o[dt]);
            o[dt] = MFMA16(P1.s, v1, o[dt]);
        }
        __builtin_amdgcn_s_setprio(0);
        __syncthreads();    // prefetch drained (next buf ready) + cur buf free
    }
#undef ASTAGE

    // ---- epilogue: ctx[b][s][h*64+d] bf16 ; o-row q = 4hi+r, l from lane 4hi+r
    const float linv = 1.f / run_l;
    float lr[4];
#pragma unroll
    for(int r=0;r<4;r++) lr[r] = __shfl(linv, 4*hi + r);
#pragma unroll
    for(int dt=0;dt<4;dt++)
#pragma unroll
        for(int r=0;r<4;r++)
            ctx[qkbase + (size_t)(q0 + hi*4 + r)*D_MODEL + dt*16 + lq] = f2bf(o[dt][r]*lr[r]);
}

// ----------------------------------------------------------------
extern "C" void kernel_launch(void* const* d_in, const int* in_sizes, int n_in,
                              void* d_out, int out_size, void* d_ws, size_t ws_size,
                              hipStream_t stream) {
    (void)in_sizes; (void)n_in; (void)out_size;
    const float* q  = (const float*)d_in[0];
    const float* k  = (const float*)d_in[1];
    const float* v  = (const float*)d_in[2];
    const float* Wq = (const float*)d_in[3];
    const float* bq = (const float*)d_in[4];
    const float* Wk = (const float*)d_in[5];
    const float* bk = (const float*)d_in[6];
    const float* Wv = (const float*)d_in[7];
    const float* bv = (const float*)d_in[8];
    const float* Wo = (const float*)d_in[9];
    const float* bo = (const float*)d_in[10];
    float* out = (float*)d_out;

    ushort_t* WS = (ushort_t*)d_ws;
    const dim3 blk(256);
    const int n4x = EX/4, n4w = EW/4;

    if(ws_size >= (size_t)(6*(size_t)EX + 3*(size_t)EW) * 2){
        // tier A: fused QKV (3 blocks/CU)
        ushort_t* Xq  = WS;
        ushort_t* Xk  = Xq + EX;
        ushort_t* Xv  = Xk + EX;
        ushort_t* Wqb = Xv + EX;
        ushort_t* Wkb = Wqb + EW;
        ushort_t* Wvb = Wkb + EW;
        ushort_t* Qp  = Wvb + EW;
        ushort_t* Kp  = Qp + EX;
        ushort_t* VtG = Kp + EX;
        ushort_t* ctx = Xq;     // free after qkv_fused
        ushort_t* Wob = Wqb;    // free after qkv_fused

        cast3<<<dim3(1024,3), blk, 0, stream>>>(q, k, v, Xq, n4x);
        cast3<<<dim3(256,3),  blk, 0, stream>>>(Wq, Wk, Wv, Wqb, n4w);
        qkv_fused<<<768, blk, 0, stream>>>(Xq,Xk,Xv, Wqb,Wkb,Wvb, bq,bk,bv, Qp,Kp,VtG);
        cast1<<<512, blk, 0, stream>>>(Wo, Wob, n4w);
        attn_fwd<<<1024, blk, 0, stream>>>(Qp, Kp, VtG, ctx);
        gemm_one<<<256, blk, 0, stream>>>(ctx, Wob, bo, 1.f, 2, out);
    } else {
        // tier C: sequential, 35.6 MB (proven size)
        ushort_t* Xb  = WS;
        ushort_t* Wb  = Xb + EX;
        ushort_t* Qp  = Wb + EW;
        ushort_t* Kp  = Qp + EX;
        ushort_t* VtG = Kp + EX;
        ushort_t* ctx = Xb;

        cast1<<<1024, blk, 0, stream>>>(q, Xb, n4x);
        cast1<<<512,  blk, 0, stream>>>(Wq, Wb, n4w);
        gemm_one<<<256, blk, 0, stream>>>(Xb, Wb, bq, QSCALE, 0, Qp);
        cast1<<<1024, blk, 0, stream>>>(k, Xb, n4x);
        cast1<<<512,  blk, 0, stream>>>(Wk, Wb, n4w);
        gemm_one<<<256, blk, 0, stream>>>(Xb, Wb, bk, 1.f, 0, Kp);
        cast1<<<1024, blk, 0, stream>>>(v, Xb, n4x);
        cast1<<<512,  blk, 0, stream>>>(Wv, Wb, n4w);
        gemm_one<<<256, blk, 0, stream>>>(Xb, Wb, bv, 1.f, 1, VtG);
        attn_fwd<<<1024, blk, 0, stream>>>(Qp, Kp, VtG, ctx);
        cast1<<<512, blk, 0, stream>>>(Wo, Wb, n4w);
        gemm_one<<<256, blk, 0, stream>>>(ctx, Wb, bo, 1.f, 2, out);
    }
}